// Round 10
// baseline (523.649 us; speedup 1.0000x reference)
//
#include <hip/hip_runtime.h>
#include <stdint.h>

#define B_ 2
#define S_ 2048
#define D_ 1024
#define H_ 16
#define DK_ 64
#define DFF_ 4096
#define M_ (B_*S_)   // 4096 rows

typedef __bf16 bf16x8 __attribute__((ext_vector_type(8)));
typedef float  f32x4  __attribute__((ext_vector_type(4)));

__device__ __forceinline__ unsigned short f2bf(float f) {
    union { float f; unsigned int u; } x; x.f = f;
    unsigned int r = x.u + 0x7FFFu + ((x.u >> 16) & 1u);
    return (unsigned short)(r >> 16);
}
__device__ __forceinline__ float bf2f(unsigned short h) {
    union { unsigned int u; float f; } x; x.u = ((unsigned int)h) << 16;
    return x.f;
}

// async global->LDS, 16B per lane; LDS dest = wave-uniform base + lane*16
__device__ __forceinline__ void gl16(const void* g, void* l) {
    __builtin_amdgcn_global_load_lds((const __attribute__((address_space(1))) unsigned int*)g,
                                     (__attribute__((address_space(3))) unsigned int*)l, 16, 0, 0);
}

// ---------------- workspace layout (bytes) ----------------
static constexpr size_t OFS_XC   = 256;                    // x canonical bf16, 8388608
static constexpr size_t OFS_MASK = OFS_XC   + 8388608;     // mask bits u64 (1 MB used)
static constexpr size_t OFS_WQKV = OFS_MASK + 8388608;     // Wq|Wk|Wv bf16, 6291456
static constexpr size_t OFS_WO   = OFS_WQKV + 6291456;     // 2097152
static constexpr size_t OFS_W1   = OFS_WO   + 2097152;     // 8388608
static constexpr size_t OFS_W2   = OFS_W1   + 8388608;     // 8388608
static constexpr size_t OFS_BIAS = OFS_W2   + 8388608;     // fp32 biases, 53248
static constexpr size_t OFS_S0   = OFS_BIAS + 53248;       // nx1 -> ctx -> nx2
static constexpr size_t OFS_S1   = OFS_S0   + 8388608;     // q
static constexpr size_t OFS_S2   = OFS_S1   + 8388608;     // k -> x2f32 (spans S2+S3)
static constexpr size_t OFS_S3   = OFS_S2   + 8388608;     // vT
static constexpr size_t OFS_H    = OFS_S3   + 8388608;     // ffn hidden bf16 / o-proj partials
// FFN2 fp32 partials (16 MiB each, all dead at FFN2 time):
//   p0 = XC+MASK span [256, 16777472)
//   p1 = S0+S1 span
//   p2 = WQKV+WO+W1 span [16777472, 33554688) — ends exactly at live W2

#define BOF_QKV 0
#define BOF_O   3072
#define BOF_2   4096
#define BOF_GA  5120
#define BOF_BA  6144
#define BOF_GF  7168
#define BOF_BF  8192
#define BOF_1   9216

// ---------------- dtype detection (one wave, parallel) ----------------
__global__ void detect_kernel(const unsigned int* __restrict__ g_attn,
                              const unsigned int* __restrict__ mask,
                              int* __restrict__ flags) {
    const int u = threadIdx.x;   // 64 lanes
    unsigned int w0 = mask[u], w1 = mask[64 + u];
    bool a32  = (w0 <= 1u) && (w1 <= 1u);
    bool af32 = ((w0 == 0u) || (w0 == 0x3F800000u)) && ((w1 == 0u) || (w1 == 0x3F800000u));
    bool a8 = true;
    #pragma unroll
    for (int j = 0; j < 4; j++)
        a8 = a8 && (((w0 >> (8*j)) & 0xFFu) <= 1u) && (((w1 >> (8*j)) & 0xFFu) <= 1u);
    int all32 = __all(a32), all8 = __all(a8), allf32 = __all(af32);
    if (u == 0) {
        unsigned int g0 = g_attn[0];
        int fm = (g0 == 0x3F800000u) ? 0 : ((g0 == 0x3C003C00u) ? 2 : 1);
        int mm = all32 ? 0 : (all8 ? 1 : (allf32 ? 2 : 3));
        flags[0] = fm; flags[1] = mm;
    }
}

// ---------------- canonicalize big float tensors -> bf16 ----------------
struct BigSrc { const void* s[7]; };  // x, Wq, Wk, Wv, Wo, W1, W2

__device__ __forceinline__ void conv4(const void* src, size_t si,
                                      unsigned short* dst, size_t di, int fm) {
    ushort4 ov;
    if (fm == 1) {
        ov = *(const ushort4*)((const unsigned short*)src + si);
    } else if (fm == 0) {
        const float* fp = (const float*)src + si;
        float4 f = *(const float4*)fp;
        ov.x = f2bf(f.x); ov.y = f2bf(f.y); ov.z = f2bf(f.z); ov.w = f2bf(f.w);
    } else {
        const _Float16* hp = (const _Float16*)src + si;
        ov.x = f2bf((float)hp[0]); ov.y = f2bf((float)hp[1]);
        ov.z = f2bf((float)hp[2]); ov.w = f2bf((float)hp[3]);
    }
    *(ushort4*)(dst + di) = ov;
}

__global__ __launch_bounds__(256) void convert_big_kernel(BigSrc srcs, char* ws) {
    const int fm = ((const int*)ws)[0];
    size_t i = ((size_t)blockIdx.x * 256 + threadIdx.x) * 4;
    if (i >= 16777216) return;
    if (i < 4194304) {
        conv4(srcs.s[0], i, (unsigned short*)(ws + OFS_XC), i, fm);
    } else if (i < 7340032) {
        size_t off = i - 4194304;
        int sub = (int)(off >> 20);
        size_t loc = off & 1048575;
        conv4(srcs.s[1 + sub], loc, (unsigned short*)(ws + OFS_WQKV), off, fm);
    } else if (i < 8388608) {
        size_t off = i - 7340032;
        conv4(srcs.s[4], off, (unsigned short*)(ws + OFS_WO), off, fm);
    } else if (i < 12582912) {
        size_t off = i - 8388608;
        conv4(srcs.s[5], off, (unsigned short*)(ws + OFS_W1), off, fm);
    } else {
        size_t off = i - 12582912;
        conv4(srcs.s[6], off, (unsigned short*)(ws + OFS_W2), off, fm);
    }
}

// ---------------- canonicalize small float tensors -> fp32 ----------------
struct SmallSrc { const void* s[10]; }; // bq,bk,bv,bo,b2,g_attn,b_attn,g_ffn,b_ffn,b1

__global__ __launch_bounds__(256) void convert_small_kernel(SmallSrc srcs, char* ws) {
    int idx = blockIdx.x * 256 + threadIdx.x;
    if (idx >= 13312) return;
    const int fm = ((const int*)ws)[0];
    int seg = idx >> 10; if (seg > 9) seg = 9;
    int loc = idx - seg * 1024;
    const void* s = srcs.s[seg];
    float f;
    if (fm == 1)      f = bf2f(((const unsigned short*)s)[loc]);
    else if (fm == 0) f = ((const float*)s)[loc];
    else              f = (float)((const _Float16*)s)[loc];
    ((float*)(ws + OFS_BIAS))[idx] = f;
}

// ---------------- mask -> bitmask u64 per (b,q,keytile) ----------------
__global__ __launch_bounds__(256) void mask_bits_kernel(const void* msrc, char* ws) {
    const int mm = ((const int*)ws)[1];
    size_t e = (size_t)blockIdx.x * 256 + threadIdx.x;   // 8388608 elements
    bool p;
    if (mm == 0)      p = ((const int*)msrc)[e] != 0;
    else if (mm == 1) p = ((const unsigned char*)msrc)[e] != 0;
    else if (mm == 2) p = ((const unsigned int*)msrc)[e] != 0;
    else              p = ((const unsigned short*)msrc)[e] != 0;
    unsigned long long bal = __ballot(p);
    if ((threadIdx.x & 63) == 0)
        ((unsigned long long*)(ws + OFS_MASK))[e >> 6] = bal;
}

// ---------------- layernorm (one block per row) ----------------
template<int IN32>
__global__ __launch_bounds__(256) void ln_kernel(const void* __restrict__ xin,
                                                 const float* __restrict__ g,
                                                 const float* __restrict__ b,
                                                 unsigned short* __restrict__ out) {
    const int row = blockIdx.x;
    const int t = threadIdx.x;
    float f0, f1, f2, f3;
    if (IN32) {
        const float* xr = (const float*)xin + (size_t)row * D_;
        float4 xv = *(const float4*)(xr + t * 4);
        f0 = xv.x; f1 = xv.y; f2 = xv.z; f3 = xv.w;
    } else {
        const unsigned short* xr = (const unsigned short*)xin + (size_t)row * D_;
        ushort4 xv = *(const ushort4*)(xr + t * 4);
        f0 = bf2f(xv.x); f1 = bf2f(xv.y); f2 = bf2f(xv.z); f3 = bf2f(xv.w);
    }
    float s = f0 + f1 + f2 + f3;
    float q = f0*f0 + f1*f1 + f2*f2 + f3*f3;
    for (int m = 1; m < 64; m <<= 1) { s += __shfl_xor(s, m); q += __shfl_xor(q, m); }
    __shared__ float red[8];
    __shared__ float mv[2];
    int w = t >> 6, u = t & 63;
    if (u == 0) { red[w*2] = s; red[w*2+1] = q; }
    __syncthreads();
    if (t == 0) {
        float S = red[0] + red[2] + red[4] + red[6];
        float Q = red[1] + red[3] + red[5] + red[7];
        float mu = S * (1.0f / D_);
        float var = Q * (1.0f / D_) - mu * mu;
        mv[0] = mu; mv[1] = rsqrtf(var + 1e-5f);
    }
    __syncthreads();
    float mu = mv[0], r = mv[1];
    int i = t * 4;
    ushort4 ov;
    ov.x = f2bf((f0 - mu) * r * g[i]   + b[i]);
    ov.y = f2bf((f1 - mu) * r * g[i+1] + b[i+1]);
    ov.z = f2bf((f2 - mu) * r * g[i+2] + b[i+2]);
    ov.w = f2bf((f3 - mu) * r * g[i+3] + b[i+3]);
    *(ushort4*)(out + (size_t)row * D_ + i) = ov;
}

// ---------------- GEMM: BK=64, 2-barrier K-loop ----------------
// EPI 1: out(bf16) = gelu_exact(acc + bias[n])
// EPI 2: qkv scatter: q,k -> [B,H,S,DK]; v -> vT[B,H,DK,S]
// EPI 5: split-K partial: z=0 reads k in [0,K1) -> out; z>=1 reads [K1+(z-1)*K2, +K2) -> p1/p2
template<int EPI>
__global__ __launch_bounds__(256) void gemm_bt_kernel(
    const unsigned short* __restrict__ A,
    const unsigned short* __restrict__ Bm,
    const float* __restrict__ bias,
    void* __restrict__ out,
    float* __restrict__ p1,
    float* __restrict__ p2,
    unsigned short* __restrict__ q_out,
    unsigned short* __restrict__ k_out,
    unsigned short* __restrict__ vT_out,
    int M, int N, int K1, int K2, int Kstride)
{
    __shared__ __attribute__((aligned(16))) unsigned short ldsA[2][4096];
    __shared__ __attribute__((aligned(16))) unsigned short ldsB[2][4096];
    const int t = threadIdx.x;
    const int w = t >> 6, u = t & 63, quad = u >> 4, l15 = u & 15;
    const int bx = blockIdx.x, by = blockIdx.y;
    const int z = (EPI == 5) ? blockIdx.z : 0;
    const int klen = (z == 0) ? K1 : K2;
    const size_t kofs = (z == 0) ? 0 : (size_t)K1 + (size_t)(z - 1) * K2;

    const int c0 = t, c1 = t + 256;  // chunk c = 16B: row=(c>>6)*16+(c&15), k=((c>>4)&3)*8
    const int ar0 = by*128 + ((c0 >> 6) << 4) + (c0 & 15), ak0 = ((c0 >> 4) & 3) * 8;
    const int ar1 = by*128 + ((c1 >> 6) << 4) + (c1 & 15), ak1 = ((c1 >> 4) & 3) * 8;
    const int br0 = bx*128 + ((c0 >> 6) << 4) + (c0 & 15);
    const int br1 = bx*128 + ((c1 >> 6) << 4) + (c1 & 15);
    const unsigned short* pa0 = A  + (size_t)ar0 * Kstride + kofs + ak0;
    const unsigned short* pa1 = A  + (size_t)ar1 * Kstride + kofs + ak1;
    const unsigned short* pb0 = Bm + (size_t)br0 * Kstride + kofs + ak0;
    const unsigned short* pb1 = Bm + (size_t)br1 * Kstride + kofs + ak1;

    const int cbase0 = (w * 64) * 8;           // wave-uniform LDS chunk bases
    const int cbase1 = (256 + w * 64) * 8;

    f32x4 acc[4][4];
    #pragma unroll
    for (int i = 0; i < 4; i++)
        #pragma unroll
        for (int j = 0; j < 4; j++) acc[i][j] = (f32x4){0.f, 0.f, 0.f, 0.f};

    const int mbase = (w >> 1) * 4;
    const int nbase = (w & 1) * 4;

    for (int k0 = 0; k0 < klen; k0 += 64) {
        __syncthreads();
        gl16(pa0,      &ldsA[0][cbase0]);
        gl16(pa1,      &ldsA[0][cbase1]);
        gl16(pb0,      &ldsB[0][cbase0]);
        gl16(pb1,      &ldsB[0][cbase1]);
        gl16(pa0 + 32, &ldsA[1][cbase0]);
        gl16(pa1 + 32, &ldsA[1][cbase1]);
        gl16(pb0 + 32, &ldsB[1][cbase0]);
        gl16(pb1 + 32, &ldsB[1][cbase1]);
        pa0 += 64; pa1 += 64; pb0 += 64; pb1 += 64;
        __syncthreads();
        #pragma unroll
        for (int sub = 0; sub < 2; sub++) {
            bf16x8 af[4], bfr[4];
            #pragma unroll
            for (int mt = 0; mt < 4; mt++) af[mt]  = *(const bf16x8*)&ldsA[sub][((mbase+mt)*64 + u) * 8];
            #pragma unroll
            for (int nt = 0; nt < 4; nt++) bfr[nt] = *(const bf16x8*)&ldsB[sub][((nbase+nt)*64 + u) * 8];
            #pragma unroll
            for (int mt = 0; mt < 4; mt++)
                #pragma unroll
                for (int nt = 0; nt < 4; nt++)
                    acc[mt][nt] = __builtin_amdgcn_mfma_f32_16x16x32_bf16(af[mt], bfr[nt], acc[mt][nt], 0, 0, 0);
        }
    }

    #pragma unroll
    for (int mt = 0; mt < 4; mt++) {
        #pragma unroll
        for (int nt = 0; nt < 4; nt++) {
            const int m0 = by*128 + (w >> 1)*64 + mt*16 + quad*4;
            const int n  = bx*128 + (w & 1)*64 + nt*16 + l15;
            float bn = 0.f;
            if constexpr (EPI != 5) bn = bias[n];
            float val[4];
            #pragma unroll
            for (int r = 0; r < 4; r++) val[r] = acc[mt][nt][r] + bn;
            if constexpr (EPI == 1) {
                #pragma unroll
                for (int r = 0; r < 4; r++) {
                    float v = val[r];
                    float ge = 0.5f * v * (1.0f + erff(v * 0.70710678118654752f));
                    ((unsigned short*)out)[(size_t)(m0 + r) * N + n] = f2bf(ge);
                }
            } else if constexpr (EPI == 2) {
                int sel = n >> 10, nn = n & 1023;
                int hh = nn >> 6, dk = nn & 63;
                int bb = m0 >> 11, ss = m0 & 2047;
                if (sel < 2) {
                    unsigned short* dst = sel == 0 ? q_out : k_out;
                    #pragma unroll
                    for (int r = 0; r < 4; r++)
                        dst[(((size_t)bb * H_ + hh) * S_ + ss + r) * DK_ + dk] = f2bf(val[r]);
                } else {
                    ushort4 pk;
                    pk.x = f2bf(val[0]); pk.y = f2bf(val[1]);
                    pk.z = f2bf(val[2]); pk.w = f2bf(val[3]);
                    *(ushort4*)&vT_out[(((size_t)bb * H_ + hh) * DK_ + dk) * S_ + ss] = pk;
                }
            } else {  // EPI 5
                float* dst = (z == 0) ? (float*)out : (z == 1 ? p1 : p2);
                #pragma unroll
                for (int r = 0; r < 4; r++)
                    dst[(size_t)(m0 + r) * N + n] = val[r];
            }
        }
    }
}

// ---------------- split-K reduce: sum partials + bias (+res) ----------------
// FINAL=0: NP=2, res bf16 (xc), out fp32 (x2f)
// FINAL=1: NP=3, res fp32 (x2f), out per flags[0]
template<int FINAL, int NP>
__global__ __launch_bounds__(256) void reduce_kernel(
    const float* __restrict__ p0, const float* __restrict__ p1,
    const float* __restrict__ p2,
    const float* __restrict__ bias, const void* __restrict__ res,
    void* __restrict__ out, const int* __restrict__ flags)
{
    size_t i = ((size_t)blockIdx.x * 256 + threadIdx.x) * 4;   // over 4096*1024
    int n = (int)(i & 1023);
    float4 a = *(const float4*)(p0 + i);
    float4 b = *(const float4*)(p1 + i);
    const float4 bi = *(const float4*)(bias + n);
    float v0 = a.x + b.x + bi.x, v1 = a.y + b.y + bi.y;
    float v2 = a.z + b.z + bi.z, v3 = a.w + b.w + bi.w;
    if constexpr (NP == 3) {
        float4 c = *(const float4*)(p2 + i);
        v0 += c.x; v1 += c.y; v2 += c.z; v3 += c.w;
    }
    if constexpr (FINAL == 0) {
        ushort4 rr = *(const ushort4*)((const unsigned short*)res + i);
        v0 += bf2f(rr.x); v1 += bf2f(rr.y); v2 += bf2f(rr.z); v3 += bf2f(rr.w);
        float4 ov = {v0, v1, v2, v3};
        *(float4*)((float*)out + i) = ov;
    } else {
        float4 rr = *(const float4*)((const float*)res + i);
        v0 += rr.x; v1 += rr.y; v2 += rr.z; v3 += rr.w;
        const int fm = flags[0];
        if (fm == 0) {
            float4 ov = {v0, v1, v2, v3};
            *(float4*)((float*)out + i) = ov;
        } else if (fm == 2) {
            _Float16* op = (_Float16*)out + i;
            op[0] = (_Float16)v0; op[1] = (_Float16)v1;
            op[2] = (_Float16)v2; op[3] = (_Float16)v3;
        } else {
            ushort4 ov;
            ov.x = f2bf(v0); ov.y = f2bf(v1); ov.z = f2bf(v2); ov.w = f2bf(v3);
            *(ushort4*)((unsigned short*)out + i) = ov;
        }
    }
}

// ---------------- flash attention v5: 512 threads / 8 waves, 16 q-rows per wave ----------------
__global__ __launch_bounds__(512) void attn_kernel(
    const unsigned short* __restrict__ q,
    const unsigned short* __restrict__ k,
    const unsigned short* __restrict__ vT,
    const unsigned long long* __restrict__ mb,
    unsigned short* __restrict__ ctx)
{
    const int blk = blockIdx.x;          // 0..511
    const int xcd = blk & 7;
    const int slot = blk >> 3;
    const int qt = slot & 15;
    const int pg = slot >> 4;
    const int p  = xcd + 8 * pg;
    const int h = p & 15, b = p >> 4;
    const int bh = b * H_ + h;

    const int t = threadIdx.x, w = t >> 6, u = t & 63, quad = u >> 4, l15 = u & 15;

    __shared__ __attribute__((aligned(16))) unsigned short Kt[512 * 8];
    __shared__ __attribute__((aligned(16))) unsigned short Vt[512 * 8];
    __shared__ __attribute__((aligned(16))) unsigned short Pw[8][16 * 72];

    const size_t base = (size_t)bh * S_ * DK_;
    const int qr0 = qt * 128 + w * 16;

    bf16x8 aq[2];
    #pragma unroll
    for (int hf = 0; hf < 2; hf++)
        aq[hf] = *(const bf16x8*)(q + base + (size_t)(qr0 + l15) * DK_ + hf*32 + quad*8);

    const int sr = t >> 3, sc = (t & 7) ^ (sr & 7);
    const unsigned short* kp = k  + base + (size_t)sr * DK_ + sc * 8;
    const unsigned short* vp = vT + base + (size_t)sr * S_  + sc * 8;
    unsigned short* lk = &Kt[(w * 64) * 8];
    unsigned short* lv = &Vt[(w * 64) * 8];

    f32x4 o[4];
    #pragma unroll
    for (int nt = 0; nt < 4; nt++) o[nt] = (f32x4){0.f, 0.f, 0.f, 0.f};
    float ls[4] = {0.f, 0.f, 0.f, 0.f};
    const float C = 0.125f * 1.4426950408889634f;

    for (int kt = 0; kt < S_ / 64; kt++) {
        unsigned long long m64[4];
        #pragma unroll
        for (int r = 0; r < 4; r++)
            m64[r] = mb[((size_t)b * S_ + qr0 + quad*4 + r) * 32 + kt];

        __syncthreads();
        gl16(kp, lk);
        gl16(vp, lv);
        kp += 64 * DK_;
        vp += 64;
        __syncthreads();

        f32x4 s4[4];
        #pragma unroll
        for (int nt = 0; nt < 4; nt++) s4[nt] = (f32x4){0.f, 0.f, 0.f, 0.f};
        #pragma unroll
        for (int nt = 0; nt < 4; nt++) {
            int rr = nt * 16 + l15;
            #pragma unroll
            for (int hf = 0; hf < 2; hf++) {
                int cc = (hf * 4 + quad) ^ (rr & 7);
                bf16x8 bk = *(const bf16x8*)&Kt[(rr * 8 + cc) * 8];
                s4[nt] = __builtin_amdgcn_mfma_f32_16x16x32_bf16(aq[hf], bk, s4[nt], 0, 0, 0);
            }
        }

        #pragma unroll
        for (int r = 0; r < 4; r++) {
            unsigned int lo = (unsigned int)m64[r], hi = (unsigned int)(m64[r] >> 32);
            #pragma unroll
            for (int nt = 0; nt < 4; nt++) {
                unsigned int word = (nt & 2) ? hi : lo;
                unsigned int bit = (word >> ((nt & 1) * 16 + l15)) & 1u;
                float arg = bit ? -20000.0f : s4[nt][r] * C;
                float e = exp2f(arg);
                ls[r] += e;
                Pw[w][(quad * 4 + r) * 72 + nt * 16 + l15] = f2bf(e);
            }
        }

        #pragma unroll
        for (int ks = 0; ks < 2; ks++) {
            bf16x8 ap = *(const bf16x8*)&Pw[w][l15 * 72 + ks * 32 + quad * 8];
            #pragma unroll
            for (int nt = 0; nt < 4; nt++) {
                int rr = nt * 16 + l15;
                int cc = (ks * 4 + quad) ^ (rr & 7);
                bf16x8 bv = *(const bf16x8*)&Vt[(rr * 8 + cc) * 8];
                o[nt] = __builtin_amdgcn_mfma_f32_16x16x32_bf16(ap, bv, o[nt], 0, 0, 0);
            }
        }
    }

    #pragma unroll
    for (int r = 0; r < 4; r++) {
        float l = ls[r];
        l += __shfl_xor(l, 1); l += __shfl_xor(l, 2);
        l += __shfl_xor(l, 4); l += __shfl_xor(l, 8);
        float inv = 1.0f / l;
        int qg = qr0 + quad * 4 + r;
        #pragma unroll
        for (int nt = 0; nt < 4; nt++)
            ctx[((size_t)b * S_ + qg) * D_ + h * DK_ + nt * 16 + l15] = f2bf(o[nt][r] * inv);
    }
}

// ---------------- launch ----------------
extern "C" void kernel_launch(void* const* d_in, const int* in_sizes, int n_in,
                              void* d_out, int out_size, void* d_ws, size_t ws_size,
                              hipStream_t stream) {
    char* ws = (char*)d_ws;

    detect_kernel<<<1, 64, 0, stream>>>((const unsigned int*)d_in[14],
                                        (const unsigned int*)d_in[1], (int*)ws);

    BigSrc bs; bs.s[0] = d_in[0]; bs.s[1] = d_in[2]; bs.s[2] = d_in[4];
    bs.s[3] = d_in[6]; bs.s[4] = d_in[8]; bs.s[5] = d_in[10]; bs.s[6] = d_in[12];
    convert_big_kernel<<<16384, 256, 0, stream>>>(bs, ws);

    SmallSrc ss;
    ss.s[0] = d_in[3];  ss.s[1] = d_in[5];  ss.s[2] = d_in[7];  ss.s[3] = d_in[9];
    ss.s[4] = d_in[13]; ss.s[5] = d_in[14]; ss.s[6] = d_in[15]; ss.s[7] = d_in[16];
    ss.s[8] = d_in[17]; ss.s[9] = d_in[11];
    convert_small_kernel<<<52, 256, 0, stream>>>(ss, ws);

    mask_bits_kernel<<<32768, 256, 0, stream>>>(d_in[1], ws);

    const unsigned short* xc  = (const unsigned short*)(ws + OFS_XC);
    const unsigned short* wqk = (const unsigned short*)(ws + OFS_WQKV);
    const unsigned short* wo  = (const unsigned short*)(ws + OFS_WO);
    const unsigned short* w1  = (const unsigned short*)(ws + OFS_W1);
    const unsigned short* w2  = (const unsigned short*)(ws + OFS_W2);
    float* biasf = (float*)(ws + OFS_BIAS);
    unsigned short* nx1 = (unsigned short*)(ws + OFS_S0);
    unsigned short* ctx = (unsigned short*)(ws + OFS_S0);
    unsigned short* nx2 = (unsigned short*)(ws + OFS_S0);
    unsigned short* qb  = (unsigned short*)(ws + OFS_S1);
    unsigned short* kb  = (unsigned short*)(ws + OFS_S2);
    unsigned short* vTb = (unsigned short*)(ws + OFS_S3);
    float*          x2f = (float*)(ws + OFS_S2);           // spans S2+S3 (16.78 MB)
    unsigned short* hb  = (unsigned short*)(ws + OFS_H);
    float* opart0 = (float*)(ws + OFS_H);                  // o-proj partial z=0
    float* opart1 = (float*)(ws + OFS_H + 16777216);       // o-proj partial z=1
    float* fpart0 = (float*)(ws + OFS_XC);                 // ffn2 partial z=0 (XC+MASK span)
    float* fpart1 = (float*)(ws + OFS_S0);                 // ffn2 partial z=1 (S0+S1 span)
    float* fpart2 = (float*)(ws + OFS_WQKV);               // ffn2 partial z=2 (WQKV+WO+W1 span)
    const unsigned long long* mbits = (const unsigned long long*)(ws + OFS_MASK);
    const int* flags = (const int*)ws;

    ln_kernel<0><<<4096, 256, 0, stream>>>(xc, biasf + BOF_GA, biasf + BOF_BA, nx1);

    gemm_bt_kernel<2><<<dim3(24, 32), 256, 0, stream>>>(
        nx1, wqk, biasf + BOF_QKV, nullptr, nullptr, nullptr, qb, kb, vTb,
        M_, 3072, 1024, 0, 1024);

    attn_kernel<<<512, 512, 0, stream>>>(qb, kb, vTb, mbits, ctx);

    // O-proj split-K=2 -> fp32 partials in H region -> reduce into x2f
    gemm_bt_kernel<5><<<dim3(8, 32, 2), 256, 0, stream>>>(
        ctx, wo, nullptr, opart0, opart1, nullptr, nullptr, nullptr, nullptr,
        M_, 1024, 512, 512, 1024);
    reduce_kernel<0, 2><<<4096, 256, 0, stream>>>(
        opart0, opart1, nullptr, biasf + BOF_O, xc, x2f, flags);

    ln_kernel<1><<<4096, 256, 0, stream>>>(x2f, biasf + BOF_GF, biasf + BOF_BF, nx2);

    gemm_bt_kernel<1><<<dim3(32, 32), 256, 0, stream>>>(
        nx2, w1, biasf + BOF_1, hb, nullptr, nullptr, nullptr, nullptr, nullptr,
        M_, 4096, 1024, 0, 1024);

    // FFN2 split-K=3 (1408+1344+1344) -> partials in 3 dead 16MiB spans -> reduce into d_out
    gemm_bt_kernel<5><<<dim3(8, 32, 3), 256, 0, stream>>>(
        hb, w2, nullptr, fpart0, fpart1, fpart2, nullptr, nullptr, nullptr,
        M_, 1024, 1408, 1344, 4096);
    reduce_kernel<1, 3><<<4096, 256, 0, stream>>>(
        fpart0, fpart1, fpart2, biasf + BOF_2, x2f, d_out, flags);
}

// Round 11
// 519.854 us; speedup vs baseline: 1.0073x; 1.0073x over previous
//
#include <hip/hip_runtime.h>
#include <stdint.h>

#define B_ 2
#define S_ 2048
#define D_ 1024
#define H_ 16
#define DK_ 64
#define DFF_ 4096
#define M_ (B_*S_)   // 4096 rows

typedef __bf16 bf16x8 __attribute__((ext_vector_type(8)));
typedef float  f32x4  __attribute__((ext_vector_type(4)));

__device__ __forceinline__ unsigned short f2bf(float f) {
    union { float f; unsigned int u; } x; x.f = f;
    unsigned int r = x.u + 0x7FFFu + ((x.u >> 16) & 1u);
    return (unsigned short)(r >> 16);
}
__device__ __forceinline__ float bf2f(unsigned short h) {
    union { unsigned int u; float f; } x; x.u = ((unsigned int)h) << 16;
    return x.f;
}

// async global->LDS, 16B per lane; LDS dest = wave-uniform base + lane*16
__device__ __forceinline__ void gl16(const void* g, void* l) {
    __builtin_amdgcn_global_load_lds((const __attribute__((address_space(1))) unsigned int*)g,
                                     (__attribute__((address_space(3))) unsigned int*)l, 16, 0, 0);
}

// ---------------- workspace layout (bytes) ----------------
static constexpr size_t OFS_XC   = 256;                    // x canonical bf16, 8388608
static constexpr size_t OFS_MASK = OFS_XC   + 8388608;     // mask bits u64 (1 MB used)
static constexpr size_t OFS_WQKV = OFS_MASK + 8388608;     // Wq|Wk|Wv bf16, 6291456
static constexpr size_t OFS_WO   = OFS_WQKV + 6291456;     // 2097152
static constexpr size_t OFS_W1   = OFS_WO   + 2097152;     // 8388608
static constexpr size_t OFS_W2   = OFS_W1   + 8388608;     // 8388608
static constexpr size_t OFS_BIAS = OFS_W2   + 8388608;     // fp32 biases, 53248
static constexpr size_t OFS_S0   = OFS_BIAS + 53248;       // nx1 -> ctx -> nx2
static constexpr size_t OFS_S1   = OFS_S0   + 8388608;     // q
static constexpr size_t OFS_S2   = OFS_S1   + 8388608;     // k -> x2f32 (spans S2+S3)
static constexpr size_t OFS_S3   = OFS_S2   + 8388608;     // vT
static constexpr size_t OFS_H    = OFS_S3   + 8388608;     // ffn hidden bf16 / o-proj partials
// FFN2 fp32 partials (16 MiB each, all dead at FFN2 time):
//   p0 = XC+MASK span, p1 = S0+S1 span, p2 = WQKV+WO+W1 span (ends exactly at live W2)

#define BOF_QKV 0
#define BOF_O   3072
#define BOF_2   4096
#define BOF_GA  5120
#define BOF_BA  6144
#define BOF_GF  7168
#define BOF_BF  8192
#define BOF_1   9216

// ---------------- dtype detection (one wave, parallel) ----------------
__global__ void detect_kernel(const unsigned int* __restrict__ g_attn,
                              const unsigned int* __restrict__ mask,
                              int* __restrict__ flags) {
    const int u = threadIdx.x;   // 64 lanes
    unsigned int w0 = mask[u], w1 = mask[64 + u];
    bool a32  = (w0 <= 1u) && (w1 <= 1u);
    bool af32 = ((w0 == 0u) || (w0 == 0x3F800000u)) && ((w1 == 0u) || (w1 == 0x3F800000u));
    bool a8 = true;
    #pragma unroll
    for (int j = 0; j < 4; j++)
        a8 = a8 && (((w0 >> (8*j)) & 0xFFu) <= 1u) && (((w1 >> (8*j)) & 0xFFu) <= 1u);
    int all32 = __all(a32), all8 = __all(a8), allf32 = __all(af32);
    if (u == 0) {
        unsigned int g0 = g_attn[0];
        int fm = (g0 == 0x3F800000u) ? 0 : ((g0 == 0x3C003C00u) ? 2 : 1);
        int mm = all32 ? 0 : (all8 ? 1 : (allf32 ? 2 : 3));
        flags[0] = fm; flags[1] = mm;
    }
}

// ---------------- canonicalize big float tensors -> bf16 ----------------
struct BigSrc { const void* s[7]; };  // x, Wq, Wk, Wv, Wo, W1, W2

__device__ __forceinline__ void conv4(const void* src, size_t si,
                                      unsigned short* dst, size_t di, int fm) {
    ushort4 ov;
    if (fm == 1) {
        ov = *(const ushort4*)((const unsigned short*)src + si);
    } else if (fm == 0) {
        const float* fp = (const float*)src + si;
        float4 f = *(const float4*)fp;
        ov.x = f2bf(f.x); ov.y = f2bf(f.y); ov.z = f2bf(f.z); ov.w = f2bf(f.w);
    } else {
        const _Float16* hp = (const _Float16*)src + si;
        ov.x = f2bf((float)hp[0]); ov.y = f2bf((float)hp[1]);
        ov.z = f2bf((float)hp[2]); ov.w = f2bf((float)hp[3]);
    }
    *(ushort4*)(dst + di) = ov;
}

__global__ __launch_bounds__(256) void convert_big_kernel(BigSrc srcs, char* ws) {
    const int fm = ((const int*)ws)[0];
    size_t i = ((size_t)blockIdx.x * 256 + threadIdx.x) * 4;
    if (i >= 16777216) return;
    if (i < 4194304) {
        conv4(srcs.s[0], i, (unsigned short*)(ws + OFS_XC), i, fm);
    } else if (i < 7340032) {
        size_t off = i - 4194304;
        int sub = (int)(off >> 20);
        size_t loc = off & 1048575;
        conv4(srcs.s[1 + sub], loc, (unsigned short*)(ws + OFS_WQKV), off, fm);
    } else if (i < 8388608) {
        size_t off = i - 7340032;
        conv4(srcs.s[4], off, (unsigned short*)(ws + OFS_WO), off, fm);
    } else if (i < 12582912) {
        size_t off = i - 8388608;
        conv4(srcs.s[5], off, (unsigned short*)(ws + OFS_W1), off, fm);
    } else {
        size_t off = i - 12582912;
        conv4(srcs.s[6], off, (unsigned short*)(ws + OFS_W2), off, fm);
    }
}

// ---------------- canonicalize small float tensors -> fp32 ----------------
struct SmallSrc { const void* s[10]; }; // bq,bk,bv,bo,b2,g_attn,b_attn,g_ffn,b_ffn,b1

__global__ __launch_bounds__(256) void convert_small_kernel(SmallSrc srcs, char* ws) {
    int idx = blockIdx.x * 256 + threadIdx.x;
    if (idx >= 13312) return;
    const int fm = ((const int*)ws)[0];
    int seg = idx >> 10; if (seg > 9) seg = 9;
    int loc = idx - seg * 1024;
    const void* s = srcs.s[seg];
    float f;
    if (fm == 1)      f = bf2f(((const unsigned short*)s)[loc]);
    else if (fm == 0) f = ((const float*)s)[loc];
    else              f = (float)((const _Float16*)s)[loc];
    ((float*)(ws + OFS_BIAS))[idx] = f;
}

// ---------------- mask -> bitmask u64 per (b,q,keytile) ----------------
__global__ __launch_bounds__(256) void mask_bits_kernel(const void* msrc, char* ws) {
    const int mm = ((const int*)ws)[1];
    size_t e = (size_t)blockIdx.x * 256 + threadIdx.x;   // 8388608 elements
    bool p;
    if (mm == 0)      p = ((const int*)msrc)[e] != 0;
    else if (mm == 1) p = ((const unsigned char*)msrc)[e] != 0;
    else if (mm == 2) p = ((const unsigned int*)msrc)[e] != 0;
    else              p = ((const unsigned short*)msrc)[e] != 0;
    unsigned long long bal = __ballot(p);
    if ((threadIdx.x & 63) == 0)
        ((unsigned long long*)(ws + OFS_MASK))[e >> 6] = bal;
}

// ---------------- layernorm (one block per row; bf16 in) ----------------
__global__ __launch_bounds__(256) void ln_kernel(const unsigned short* __restrict__ xin,
                                                 const float* __restrict__ g,
                                                 const float* __restrict__ b,
                                                 unsigned short* __restrict__ out) {
    const int row = blockIdx.x;
    const int t = threadIdx.x;
    const unsigned short* xr = xin + (size_t)row * D_;
    ushort4 xv = *(const ushort4*)(xr + t * 4);
    float f0 = bf2f(xv.x), f1 = bf2f(xv.y), f2 = bf2f(xv.z), f3 = bf2f(xv.w);
    float s = f0 + f1 + f2 + f3;
    float q = f0*f0 + f1*f1 + f2*f2 + f3*f3;
    for (int m = 1; m < 64; m <<= 1) { s += __shfl_xor(s, m); q += __shfl_xor(q, m); }
    __shared__ float red[8];
    __shared__ float mv[2];
    int w = t >> 6, u = t & 63;
    if (u == 0) { red[w*2] = s; red[w*2+1] = q; }
    __syncthreads();
    if (t == 0) {
        float S = red[0] + red[2] + red[4] + red[6];
        float Q = red[1] + red[3] + red[5] + red[7];
        float mu = S * (1.0f / D_);
        float var = Q * (1.0f / D_) - mu * mu;
        mv[0] = mu; mv[1] = rsqrtf(var + 1e-5f);
    }
    __syncthreads();
    float mu = mv[0], r = mv[1];
    int i = t * 4;
    ushort4 ov;
    ov.x = f2bf((f0 - mu) * r * g[i]   + b[i]);
    ov.y = f2bf((f1 - mu) * r * g[i+1] + b[i+1]);
    ov.z = f2bf((f2 - mu) * r * g[i+2] + b[i+2]);
    ov.w = f2bf((f3 - mu) * r * g[i+3] + b[i+3]);
    *(ushort4*)(out + (size_t)row * D_ + i) = ov;
}

// ---------------- fused: o-proj split-K reduce + residual + LN2 ----------------
// one block per row (1024 floats = 256 thr x 4); writes x2f (fp32) and nx2 (bf16)
__global__ __launch_bounds__(256) void fused_rln_kernel(
    const float* __restrict__ p0, const float* __restrict__ p1,
    const float* __restrict__ bias, const unsigned short* __restrict__ resbf,
    float* __restrict__ x2f_out,
    const float* __restrict__ g, const float* __restrict__ bl,
    unsigned short* __restrict__ nx_out)
{
    const int row = blockIdx.x;
    const int t = threadIdx.x;
    const size_t i = (size_t)row * D_ + t * 4;
    float4 a = *(const float4*)(p0 + i);
    float4 b = *(const float4*)(p1 + i);
    const float4 bi = *(const float4*)(bias + t * 4);
    ushort4 rr = *(const ushort4*)(resbf + i);
    float v0 = a.x + b.x + bi.x + bf2f(rr.x);
    float v1 = a.y + b.y + bi.y + bf2f(rr.y);
    float v2 = a.z + b.z + bi.z + bf2f(rr.z);
    float v3 = a.w + b.w + bi.w + bf2f(rr.w);
    float4 ov = {v0, v1, v2, v3};
    *(float4*)(x2f_out + i) = ov;

    float s = v0 + v1 + v2 + v3;
    float q = v0*v0 + v1*v1 + v2*v2 + v3*v3;
    for (int m = 1; m < 64; m <<= 1) { s += __shfl_xor(s, m); q += __shfl_xor(q, m); }
    __shared__ float red[8];
    __shared__ float mv[2];
    int w = t >> 6, u = t & 63;
    if (u == 0) { red[w*2] = s; red[w*2+1] = q; }
    __syncthreads();
    if (t == 0) {
        float S = red[0] + red[2] + red[4] + red[6];
        float Q = red[1] + red[3] + red[5] + red[7];
        float mu = S * (1.0f / D_);
        float var = Q * (1.0f / D_) - mu * mu;
        mv[0] = mu; mv[1] = rsqrtf(var + 1e-5f);
    }
    __syncthreads();
    float mu = mv[0], r = mv[1];
    int idx = t * 4;
    ushort4 onv;
    onv.x = f2bf((v0 - mu) * r * g[idx]   + bl[idx]);
    onv.y = f2bf((v1 - mu) * r * g[idx+1] + bl[idx+1]);
    onv.z = f2bf((v2 - mu) * r * g[idx+2] + bl[idx+2]);
    onv.w = f2bf((v3 - mu) * r * g[idx+3] + bl[idx+3]);
    *(ushort4*)(nx_out + i) = onv;
}

// ---------------- GEMM: BK=64, 2-barrier K-loop ----------------
// EPI 1: out(bf16) = gelu_exact(acc + bias[n])
// EPI 2: qkv scatter: q,k -> [B,H,S,DK]; v -> vT[B,H,DK,S]
// EPI 5: split-K partial: z=0 reads k in [0,K1) -> out; z>=1 reads [K1+(z-1)*K2, +K2) -> p1/p2
template<int EPI>
__global__ __launch_bounds__(256) void gemm_bt_kernel(
    const unsigned short* __restrict__ A,
    const unsigned short* __restrict__ Bm,
    const float* __restrict__ bias,
    void* __restrict__ out,
    float* __restrict__ p1,
    float* __restrict__ p2,
    unsigned short* __restrict__ q_out,
    unsigned short* __restrict__ k_out,
    unsigned short* __restrict__ vT_out,
    int M, int N, int K1, int K2, int Kstride)
{
    __shared__ __attribute__((aligned(16))) unsigned short ldsA[2][4096];
    __shared__ __attribute__((aligned(16))) unsigned short ldsB[2][4096];
    const int t = threadIdx.x;
    const int w = t >> 6, u = t & 63, quad = u >> 4, l15 = u & 15;
    const int bx = blockIdx.x, by = blockIdx.y;
    const int z = (EPI == 5) ? blockIdx.z : 0;
    const int klen = (z == 0) ? K1 : K2;
    const size_t kofs = (z == 0) ? 0 : (size_t)K1 + (size_t)(z - 1) * K2;

    const int c0 = t, c1 = t + 256;  // chunk c = 16B: row=(c>>6)*16+(c&15), k=((c>>4)&3)*8
    const int ar0 = by*128 + ((c0 >> 6) << 4) + (c0 & 15), ak0 = ((c0 >> 4) & 3) * 8;
    const int ar1 = by*128 + ((c1 >> 6) << 4) + (c1 & 15), ak1 = ((c1 >> 4) & 3) * 8;
    const int br0 = bx*128 + ((c0 >> 6) << 4) + (c0 & 15);
    const int br1 = bx*128 + ((c1 >> 6) << 4) + (c1 & 15);
    const unsigned short* pa0 = A  + (size_t)ar0 * Kstride + kofs + ak0;
    const unsigned short* pa1 = A  + (size_t)ar1 * Kstride + kofs + ak1;
    const unsigned short* pb0 = Bm + (size_t)br0 * Kstride + kofs + ak0;
    const unsigned short* pb1 = Bm + (size_t)br1 * Kstride + kofs + ak1;

    const int cbase0 = (w * 64) * 8;           // wave-uniform LDS chunk bases
    const int cbase1 = (256 + w * 64) * 8;

    f32x4 acc[4][4];
    #pragma unroll
    for (int i = 0; i < 4; i++)
        #pragma unroll
        for (int j = 0; j < 4; j++) acc[i][j] = (f32x4){0.f, 0.f, 0.f, 0.f};

    const int mbase = (w >> 1) * 4;
    const int nbase = (w & 1) * 4;

    for (int k0 = 0; k0 < klen; k0 += 64) {
        __syncthreads();
        gl16(pa0,      &ldsA[0][cbase0]);
        gl16(pa1,      &ldsA[0][cbase1]);
        gl16(pb0,      &ldsB[0][cbase0]);
        gl16(pb1,      &ldsB[0][cbase1]);
        gl16(pa0 + 32, &ldsA[1][cbase0]);
        gl16(pa1 + 32, &ldsA[1][cbase1]);
        gl16(pb0 + 32, &ldsB[1][cbase0]);
        gl16(pb1 + 32, &ldsB[1][cbase1]);
        pa0 += 64; pa1 += 64; pb0 += 64; pb1 += 64;
        __syncthreads();
        #pragma unroll
        for (int sub = 0; sub < 2; sub++) {
            bf16x8 af[4], bfr[4];
            #pragma unroll
            for (int mt = 0; mt < 4; mt++) af[mt]  = *(const bf16x8*)&ldsA[sub][((mbase+mt)*64 + u) * 8];
            #pragma unroll
            for (int nt = 0; nt < 4; nt++) bfr[nt] = *(const bf16x8*)&ldsB[sub][((nbase+nt)*64 + u) * 8];
            #pragma unroll
            for (int mt = 0; mt < 4; mt++)
                #pragma unroll
                for (int nt = 0; nt < 4; nt++)
                    acc[mt][nt] = __builtin_amdgcn_mfma_f32_16x16x32_bf16(af[mt], bfr[nt], acc[mt][nt], 0, 0, 0);
        }
    }

    #pragma unroll
    for (int mt = 0; mt < 4; mt++) {
        #pragma unroll
        for (int nt = 0; nt < 4; nt++) {
            const int m0 = by*128 + (w >> 1)*64 + mt*16 + quad*4;
            const int n  = bx*128 + (w & 1)*64 + nt*16 + l15;
            float bn = 0.f;
            if constexpr (EPI != 5) bn = bias[n];
            float val[4];
            #pragma unroll
            for (int r = 0; r < 4; r++) val[r] = acc[mt][nt][r] + bn;
            if constexpr (EPI == 1) {
                #pragma unroll
                for (int r = 0; r < 4; r++) {
                    float v = val[r];
                    float ge = 0.5f * v * (1.0f + erff(v * 0.70710678118654752f));
                    ((unsigned short*)out)[(size_t)(m0 + r) * N + n] = f2bf(ge);
                }
            } else if constexpr (EPI == 2) {
                int sel = n >> 10, nn = n & 1023;
                int hh = nn >> 6, dk = nn & 63;
                int bb = m0 >> 11, ss = m0 & 2047;
                if (sel < 2) {
                    unsigned short* dst = sel == 0 ? q_out : k_out;
                    #pragma unroll
                    for (int r = 0; r < 4; r++)
                        dst[(((size_t)bb * H_ + hh) * S_ + ss + r) * DK_ + dk] = f2bf(val[r]);
                } else {
                    ushort4 pk;
                    pk.x = f2bf(val[0]); pk.y = f2bf(val[1]);
                    pk.z = f2bf(val[2]); pk.w = f2bf(val[3]);
                    *(ushort4*)&vT_out[(((size_t)bb * H_ + hh) * DK_ + dk) * S_ + ss] = pk;
                }
            } else {  // EPI 5
                float* dst = (z == 0) ? (float*)out : (z == 1 ? p1 : p2);
                #pragma unroll
                for (int r = 0; r < 4; r++)
                    dst[(size_t)(m0 + r) * N + n] = val[r];
            }
        }
    }
}

// ---------------- final split-K reduce: p0+p1+p2+bias+res -> d_out ----------------
__global__ __launch_bounds__(256) void reduce_final_kernel(
    const float* __restrict__ p0, const float* __restrict__ p1,
    const float* __restrict__ p2,
    const float* __restrict__ bias, const float* __restrict__ res,
    void* __restrict__ out, const int* __restrict__ flags)
{
    size_t i = ((size_t)blockIdx.x * 256 + threadIdx.x) * 4;   // over 4096*1024
    int n = (int)(i & 1023);
    float4 a = *(const float4*)(p0 + i);
    float4 b = *(const float4*)(p1 + i);
    float4 c = *(const float4*)(p2 + i);
    const float4 bi = *(const float4*)(bias + n);
    float4 rr = *(const float4*)(res + i);
    float v0 = a.x + b.x + c.x + bi.x + rr.x;
    float v1 = a.y + b.y + c.y + bi.y + rr.y;
    float v2 = a.z + b.z + c.z + bi.z + rr.z;
    float v3 = a.w + b.w + c.w + bi.w + rr.w;
    const int fm = flags[0];
    if (fm == 0) {
        float4 ov = {v0, v1, v2, v3};
        *(float4*)((float*)out + i) = ov;
    } else if (fm == 2) {
        _Float16* op = (_Float16*)out + i;
        op[0] = (_Float16)v0; op[1] = (_Float16)v1;
        op[2] = (_Float16)v2; op[3] = (_Float16)v3;
    } else {
        ushort4 ov;
        ov.x = f2bf(v0); ov.y = f2bf(v1); ov.z = f2bf(v2); ov.w = f2bf(v3);
        *(ushort4*)((unsigned short*)out + i) = ov;
    }
}

// ---------------- flash attention v6: 8 waves, dbuf K/V, single barrier + prefetch ----------------
__global__ __launch_bounds__(512) void attn_kernel(
    const unsigned short* __restrict__ q,
    const unsigned short* __restrict__ k,
    const unsigned short* __restrict__ vT,
    const unsigned long long* __restrict__ mb,
    unsigned short* __restrict__ ctx)
{
    const int blk = blockIdx.x;          // 0..511
    const int xcd = blk & 7;
    const int slot = blk >> 3;
    const int qt = slot & 15;
    const int pg = slot >> 4;
    const int p  = xcd + 8 * pg;
    const int h = p & 15, b = p >> 4;
    const int bh = b * H_ + h;

    const int t = threadIdx.x, w = t >> 6, u = t & 63, quad = u >> 4, l15 = u & 15;

    __shared__ __attribute__((aligned(16))) unsigned short Kt[2][4096];
    __shared__ __attribute__((aligned(16))) unsigned short Vt[2][4096];
    __shared__ __attribute__((aligned(16))) unsigned short Pw[8][16 * 72];

    const size_t base = (size_t)bh * S_ * DK_;
    const int qr0 = qt * 128 + w * 16;

    bf16x8 aq[2];
    #pragma unroll
    for (int hf = 0; hf < 2; hf++)
        aq[hf] = *(const bf16x8*)(q + base + (size_t)(qr0 + l15) * DK_ + hf*32 + quad*8);

    // staging: one 16B chunk per thread; swizzled source so slot s holds chunk (r, c^(r&7))
    const int sr = t >> 3, sc = (t & 7) ^ (sr & 7);
    const unsigned short* kp = k  + base + (size_t)sr * DK_ + sc * 8;
    const unsigned short* vp = vT + base + (size_t)sr * S_  + sc * 8;
    const int cb = (w * 64) * 8;   // wave-uniform base; lane lands at +lane*16B

    f32x4 o[4];
    #pragma unroll
    for (int nt = 0; nt < 4; nt++) o[nt] = (f32x4){0.f, 0.f, 0.f, 0.f};
    float ls[4] = {0.f, 0.f, 0.f, 0.f};
    const float C = 0.125f * 1.4426950408889634f;

    // prologue: stage kt=0 -> buf 0
    gl16(kp, &Kt[0][cb]);
    gl16(vp, &Vt[0][cb]);
    kp += 64 * DK_;
    vp += 64;

    for (int kt = 0; kt < S_ / 64; kt++) {
        const int cur = kt & 1;
        unsigned long long m64[4];
        #pragma unroll
        for (int r = 0; r < 4; r++)
            m64[r] = mb[((size_t)b * S_ + qr0 + quad*4 + r) * 32 + kt];

        __syncthreads();   // drains gl16(kt) — issued one full compute phase ago (except kt=0)

        if (kt + 1 < S_ / 64) {   // prefetch kt+1 into other buffer (covered by compute below)
            gl16(kp, &Kt[cur ^ 1][cb]);
            gl16(vp, &Vt[cur ^ 1][cb]);
            kp += 64 * DK_;
            vp += 64;
        }

        // ---- S = Q K^T ----
        f32x4 s4[4];
        #pragma unroll
        for (int nt = 0; nt < 4; nt++) s4[nt] = (f32x4){0.f, 0.f, 0.f, 0.f};
        #pragma unroll
        for (int nt = 0; nt < 4; nt++) {
            int rr = nt * 16 + l15;
            #pragma unroll
            for (int hf = 0; hf < 2; hf++) {
                int cc = (hf * 4 + quad) ^ (rr & 7);
                bf16x8 bk = *(const bf16x8*)&Kt[cur][(rr * 8 + cc) * 8];
                s4[nt] = __builtin_amdgcn_mfma_f32_16x16x32_bf16(aq[hf], bk, s4[nt], 0, 0, 0);
            }
        }

        // ---- mask + exp + P to LDS ----
        #pragma unroll
        for (int r = 0; r < 4; r++) {
            unsigned int lo = (unsigned int)m64[r], hi = (unsigned int)(m64[r] >> 32);
            #pragma unroll
            for (int nt = 0; nt < 4; nt++) {
                unsigned int word = (nt & 2) ? hi : lo;
                unsigned int bit = (word >> ((nt & 1) * 16 + l15)) & 1u;
                float arg = bit ? -20000.0f : s4[nt][r] * C;
                float e = exp2f(arg);
                ls[r] += e;
                Pw[w][(quad * 4 + r) * 72 + nt * 16 + l15] = f2bf(e);
            }
        }

        // ---- O += P V (same-wave LDS RAW; compiler inserts lgkmcnt) ----
        #pragma unroll
        for (int ks = 0; ks < 2; ks++) {
            bf16x8 ap = *(const bf16x8*)&Pw[w][l15 * 72 + ks * 32 + quad * 8];
            #pragma unroll
            for (int nt = 0; nt < 4; nt++) {
                int rr = nt * 16 + l15;
                int cc = (ks * 4 + quad) ^ (rr & 7);
                bf16x8 bv = *(const bf16x8*)&Vt[cur][(rr * 8 + cc) * 8];
                o[nt] = __builtin_amdgcn_mfma_f32_16x16x32_bf16(ap, bv, o[nt], 0, 0, 0);
            }
        }
    }

    #pragma unroll
    for (int r = 0; r < 4; r++) {
        float l = ls[r];
        l += __shfl_xor(l, 1); l += __shfl_xor(l, 2);
        l += __shfl_xor(l, 4); l += __shfl_xor(l, 8);
        float inv = 1.0f / l;
        int qg = qr0 + quad * 4 + r;
        #pragma unroll
        for (int nt = 0; nt < 4; nt++)
            ctx[((size_t)b * S_ + qg) * D_ + h * DK_ + nt * 16 + l15] = f2bf(o[nt][r] * inv);
    }
}

// ---------------- launch ----------------
extern "C" void kernel_launch(void* const* d_in, const int* in_sizes, int n_in,
                              void* d_out, int out_size, void* d_ws, size_t ws_size,
                              hipStream_t stream) {
    char* ws = (char*)d_ws;

    detect_kernel<<<1, 64, 0, stream>>>((const unsigned int*)d_in[14],
                                        (const unsigned int*)d_in[1], (int*)ws);

    BigSrc bs; bs.s[0] = d_in[0]; bs.s[1] = d_in[2]; bs.s[2] = d_in[4];
    bs.s[3] = d_in[6]; bs.s[4] = d_in[8]; bs.s[5] = d_in[10]; bs.s[6] = d_in[12];
    convert_big_kernel<<<16384, 256, 0, stream>>>(bs, ws);

    SmallSrc ss;
    ss.s[0] = d_in[3];  ss.s[1] = d_in[5];  ss.s[2] = d_in[7];  ss.s[3] = d_in[9];
    ss.s[4] = d_in[13]; ss.s[5] = d_in[14]; ss.s[6] = d_in[15]; ss.s[7] = d_in[16];
    ss.s[8] = d_in[17]; ss.s[9] = d_in[11];
    convert_small_kernel<<<52, 256, 0, stream>>>(ss, ws);

    mask_bits_kernel<<<32768, 256, 0, stream>>>(d_in[1], ws);

    const unsigned short* xc  = (const unsigned short*)(ws + OFS_XC);
    const unsigned short* wqk = (const unsigned short*)(ws + OFS_WQKV);
    const unsigned short* wo  = (const unsigned short*)(ws + OFS_WO);
    const unsigned short* w1  = (const unsigned short*)(ws + OFS_W1);
    const unsigned short* w2  = (const unsigned short*)(ws + OFS_W2);
    float* biasf = (float*)(ws + OFS_BIAS);
    unsigned short* nx1 = (unsigned short*)(ws + OFS_S0);
    unsigned short* ctx = (unsigned short*)(ws + OFS_S0);
    unsigned short* nx2 = (unsigned short*)(ws + OFS_S0);
    unsigned short* qb  = (unsigned short*)(ws + OFS_S1);
    unsigned short* kb  = (unsigned short*)(ws + OFS_S2);
    unsigned short* vTb = (unsigned short*)(ws + OFS_S3);
    float*          x2f = (float*)(ws + OFS_S2);           // spans S2+S3 (16.78 MB)
    unsigned short* hb  = (unsigned short*)(ws + OFS_H);
    float* opart0 = (float*)(ws + OFS_H);                  // o-proj partial z=0
    float* opart1 = (float*)(ws + OFS_H + 16777216);       // o-proj partial z=1
    float* fpart0 = (float*)(ws + OFS_XC);                 // ffn2 partial z=0 (XC+MASK span)
    float* fpart1 = (float*)(ws + OFS_S0);                 // ffn2 partial z=1 (S0+S1 span)
    float* fpart2 = (float*)(ws + OFS_WQKV);               // ffn2 partial z=2 (WQKV+WO+W1 span)
    const unsigned long long* mbits = (const unsigned long long*)(ws + OFS_MASK);
    const int* flags = (const int*)ws;

    ln_kernel<<<4096, 256, 0, stream>>>(xc, biasf + BOF_GA, biasf + BOF_BA, nx1);

    gemm_bt_kernel<2><<<dim3(24, 32), 256, 0, stream>>>(
        nx1, wqk, biasf + BOF_QKV, nullptr, nullptr, nullptr, qb, kb, vTb,
        M_, 3072, 1024, 0, 1024);

    attn_kernel<<<512, 512, 0, stream>>>(qb, kb, vTb, mbits, ctx);

    // O-proj split-K=2 -> fp32 partials in H region -> fused reduce+residual+LN2
    gemm_bt_kernel<5><<<dim3(8, 32, 2), 256, 0, stream>>>(
        ctx, wo, nullptr, opart0, opart1, nullptr, nullptr, nullptr, nullptr,
        M_, 1024, 512, 512, 1024);
    fused_rln_kernel<<<4096, 256, 0, stream>>>(
        opart0, opart1, biasf + BOF_O, xc, x2f,
        biasf + BOF_GF, biasf + BOF_BF, nx2);

    gemm_bt_kernel<1><<<dim3(32, 32), 256, 0, stream>>>(
        nx2, w1, biasf + BOF_1, hb, nullptr, nullptr, nullptr, nullptr, nullptr,
        M_, 4096, 1024, 0, 1024);

    // FFN2 split-K=3 (1408+1344+1344) -> partials in 3 dead 16MiB spans -> reduce into d_out
    gemm_bt_kernel<5><<<dim3(8, 32, 3), 256, 0, stream>>>(
        hb, w2, nullptr, fpart0, fpart1, fpart2, nullptr, nullptr, nullptr,
        M_, 1024, 1408, 1344, 4096);
    reduce_final_kernel<<<4096, 256, 0, stream>>>(
        fpart0, fpart1, fpart2, biasf + BOF_2, x2f, d_out, flags);
}